// Round 3
// baseline (691.956 us; speedup 1.0000x reference)
//
#include <hip/hip_runtime.h>
#include <hip/hip_bf16.h>

typedef __bf16 bf16_t;
typedef bf16_t bf16x8 __attribute__((ext_vector_type(8)));
typedef float f32x4 __attribute__((ext_vector_type(4)));

#define GASP const __attribute__((address_space(1))) void*
#define LASP __attribute__((address_space(3))) void*

constexpr int BM = 128, BN = 128, BK = 32;  // BK = bf16 sub-tile K (64-byte LDS rows)
constexpr int D_DIM = 1024;
constexpr int S_DIM = 4096;
constexpr int B_DIM = 4;

// ---------------- elementwise cast X: fp32 -> bf16 ----------------
__global__ void cast_f32_bf16(const float* __restrict__ in, bf16_t* __restrict__ out) {
  size_t i = ((size_t)blockIdx.x * blockDim.x + threadIdx.x) * 8;
  float4 a = *(const float4*)(in + i);
  float4 b = *(const float4*)(in + i + 4);
  bf16x8 o;
  o[0] = (bf16_t)a.x; o[1] = (bf16_t)a.y; o[2] = (bf16_t)a.z; o[3] = (bf16_t)a.w;
  o[4] = (bf16_t)b.x; o[5] = (bf16_t)b.y; o[6] = (bf16_t)b.z; o[7] = (bf16_t)b.w;
  *(bf16x8*)(out + i) = o;
}

// ---------------- transpose + cast weight: [1024][1024] f32 -> bf16 transposed ----
__global__ void transpose_cast_1024(const float* __restrict__ in, bf16_t* __restrict__ out) {
  __shared__ float t[32][33];
  int x0 = blockIdx.x * 32, y0 = blockIdx.y * 32;
#pragma unroll
  for (int i = 0; i < 32; i += 8)
    t[threadIdx.y + i][threadIdx.x] =
        in[(size_t)(y0 + threadIdx.y + i) * D_DIM + (x0 + threadIdx.x)];
  __syncthreads();
#pragma unroll
  for (int i = 0; i < 32; i += 8)
    out[(size_t)(x0 + threadIdx.y + i) * D_DIM + (y0 + threadIdx.x)] =
        (bf16_t)t[threadIdx.x][threadIdx.y + i];
}

// ---------------- staging: 128 rows x 64 bytes -> LDS via global_load_lds (16B/lane) ------
// Works for bf16 (64B = 32 elems) and fp8 (64B = 64 elems): geometry is byte-identical.
__device__ __forceinline__ void stage128x64B(const char* __restrict__ g, int ldb,
                                             char* lds, int tid) {
  int r = tid >> 2;
  int c = (tid & 3) * 16;
  const char* g0 = g + (size_t)r * ldb + c;
  const char* g1 = g0 + (size_t)64 * ldb;
  char* l0 = lds + (tid >> 6) * 1024;  // wave-uniform base; HW adds lane*16B
  __builtin_amdgcn_global_load_lds((GASP)g0, (LASP)l0, 16, 0, 0);
  __builtin_amdgcn_global_load_lds((GASP)g1, (LASP)(l0 + 4096), 16, 0, 0);
}

// ---------------- gemm_bt (bf16): C[M,N] = A[M,K] * Bt[N,K]^T, fp32 acc ---------
// EPI 0: fused QKV projection epilogue — Q,K emitted as fp8 e4m3 row-major (+bias),
//        V emitted bf16 transposed into Vt[b][d][s] (+bias).
// EPI 3: fp32 out (PV). SWAP: x = row-blocks for B-panel L2 locality.
template <int EPI, bool SWAP>
__global__ __launch_bounds__(256) void gemm_bt(
    const bf16_t* __restrict__ A, const bf16_t* __restrict__ Bt,
    void* __restrict__ C0, void* __restrict__ C1, void* __restrict__ C2,
    const float* __restrict__ b0, const float* __restrict__ b1, const float* __restrict__ b2,
    int K, int lda, int ldb, int ldc,
    size_t sA, size_t sB, size_t sC) {
  __shared__ bf16_t As[2 * BM * BK];  // two 128x32 halves, 16 KB
  __shared__ bf16_t Bs[2 * BN * BK];
  const int tid = threadIdx.x;
  const int lane = tid & 63;
  const int w = tid >> 6;
  const int wr = (w >> 1) * 64;
  const int wc = (w & 1) * 64;
  const int fm = lane & 15;
  const int fko = (lane >> 4) * 8;

  const int bx = SWAP ? blockIdx.y : blockIdx.x;
  const int by = SWAP ? blockIdx.x : blockIdx.y;

  const bf16_t* Ag = A + (size_t)blockIdx.z * sA + (size_t)by * BM * lda;
  const bf16_t* Bg = Bt + (size_t)blockIdx.z * sB + (size_t)bx * BN * ldb;

  f32x4 acc[4][4] = {};

  for (int k0 = 0; k0 < K; k0 += 2 * BK) {
    stage128x64B((const char*)(Ag + k0), lda * 2, (char*)As, tid);
    stage128x64B((const char*)(Ag + k0 + BK), lda * 2, (char*)(As + BM * BK), tid);
    stage128x64B((const char*)(Bg + k0), ldb * 2, (char*)Bs, tid);
    stage128x64B((const char*)(Bg + k0 + BK), ldb * 2, (char*)(Bs + BN * BK), tid);
    __syncthreads();
#pragma unroll
    for (int h = 0; h < 2; ++h) {
      const bf16_t* as = As + h * BM * BK;
      const bf16_t* bs = Bs + h * BN * BK;
      bf16x8 af[4], bfr[4];
#pragma unroll
      for (int i = 0; i < 4; ++i)
        af[i] = *(const bf16x8*)&as[(wr + i * 16 + fm) * BK + fko];
#pragma unroll
      for (int j = 0; j < 4; ++j)
        bfr[j] = *(const bf16x8*)&bs[(wc + j * 16 + fm) * BK + fko];
#pragma unroll
      for (int i = 0; i < 4; ++i)
#pragma unroll
        for (int j = 0; j < 4; ++j)
          acc[i][j] = __builtin_amdgcn_mfma_f32_16x16x32_bf16(af[i], bfr[j], acc[i][j], 0, 0, 0);
    }
    __syncthreads();
  }

  // epilogue: C/D layout col=lane&15, row=(lane>>4)*4+reg
  const int row0 = by * BM + wr + (lane >> 4) * 4;
  const int col0 = bx * BN + wc + fm;

  if constexpr (EPI == 0) {
    const int seg = (bx * BN) >> 10;  // 0=Q, 1=K, 2=V (block cols are 128-aligned)
    const float* bias = (seg == 0) ? b0 : (seg == 1) ? b1 : b2;
#pragma unroll
    for (int i = 0; i < 4; ++i) {
#pragma unroll
      for (int j = 0; j < 4; ++j) {
        const int n = col0 + j * 16;
        const int nl = n & 1023;
        const float bv = bias[nl];
#pragma unroll
        for (int r = 0; r < 4; ++r) {
          const int m = row0 + i * 16 + r;
          float v = acc[i][j][r] + bv;
          if (seg < 2) {
            // Q,K -> fp8 e4m3 (OCP), row-major [16384][1024]
            unsigned char q8 =
                (unsigned char)(__builtin_amdgcn_cvt_pk_fp8_f32(v, v, 0, false) & 0xff);
            ((unsigned char*)(seg == 0 ? C0 : C1))[(size_t)m * D_DIM + nl] = q8;
          } else {
            // Vt[b][d][s]: b = m>>12, s = m&4095
            ((bf16_t*)C2)[((size_t)(m >> 12) << 22) + (size_t)nl * S_DIM + (m & (S_DIM - 1))] =
                (bf16_t)v;
          }
        }
      }
    }
  } else {
#pragma unroll
    for (int i = 0; i < 4; ++i) {
#pragma unroll
      for (int j = 0; j < 4; ++j) {
        const int n = col0 + j * 16;
#pragma unroll
        for (int r = 0; r < 4; ++r) {
          const int m = row0 + i * 16 + r;
          ((float*)C0 + (size_t)blockIdx.z * sC)[(size_t)m * ldc + n] = acc[i][j][r];
        }
      }
    }
  }
}

// ---------------- scores: P = sigmoid(scale * Q @ K^T), fp8 e4m3 inputs ----------
// Same 128x128 block / 4-wave structure; LDS rows are 64 B = 64 fp8 elems (BK=64),
// two halves per barrier => effective K-step 128, 64 MFMAs per barrier pair.
__global__ __launch_bounds__(256) void gemm_fp8_sig(
    const unsigned char* __restrict__ Q, const unsigned char* __restrict__ Kt,
    bf16_t* __restrict__ P, float scale, size_t sA, size_t sB, size_t sC) {
  __shared__ char As[2 * 128 * 64];  // 16 KB
  __shared__ char Bs[2 * 128 * 64];
  const int tid = threadIdx.x;
  const int lane = tid & 63;
  const int w = tid >> 6;
  const int wr = (w >> 1) * 64;
  const int wc = (w & 1) * 64;
  const int fm = lane & 15;
  const int ko8 = (lane >> 4) * 8;  // byte offset of this lane's 8-elem k-chunk

  const unsigned char* Qg = Q + (size_t)blockIdx.z * sA + (size_t)blockIdx.y * BM * D_DIM;
  const unsigned char* Kg = Kt + (size_t)blockIdx.z * sB + (size_t)blockIdx.x * BN * D_DIM;

  f32x4 acc[4][4] = {};

  for (int k0 = 0; k0 < D_DIM; k0 += 128) {
    stage128x64B((const char*)(Qg + k0), D_DIM, As, tid);
    stage128x64B((const char*)(Qg + k0 + 64), D_DIM, As + 8192, tid);
    stage128x64B((const char*)(Kg + k0), D_DIM, Bs, tid);
    stage128x64B((const char*)(Kg + k0 + 64), D_DIM, Bs + 8192, tid);
    __syncthreads();
#pragma unroll
    for (int h = 0; h < 2; ++h) {
      const char* as = As + h * 8192;
      const char* bs = Bs + h * 8192;
      long a0[4], a1[4], bq0[4], bq1[4];
#pragma unroll
      for (int i = 0; i < 4; ++i) {
        const char* r = &as[(wr + i * 16 + fm) * 64 + ko8];
        a0[i] = *(const long*)r;
        a1[i] = *(const long*)(r + 32);
      }
#pragma unroll
      for (int j = 0; j < 4; ++j) {
        const char* r = &bs[(wc + j * 16 + fm) * 64 + ko8];
        bq0[j] = *(const long*)r;
        bq1[j] = *(const long*)(r + 32);
      }
#pragma unroll
      for (int i = 0; i < 4; ++i)
#pragma unroll
        for (int j = 0; j < 4; ++j) {
          acc[i][j] = __builtin_amdgcn_mfma_f32_16x16x32_fp8_fp8(a0[i], bq0[j], acc[i][j], 0, 0, 0);
          acc[i][j] = __builtin_amdgcn_mfma_f32_16x16x32_fp8_fp8(a1[i], bq1[j], acc[i][j], 0, 0, 0);
        }
    }
    __syncthreads();
  }

  const int row0 = blockIdx.y * BM + wr + (lane >> 4) * 4;
  const int col0 = blockIdx.x * BN + wc + fm;
  bf16_t* C = P + (size_t)blockIdx.z * sC;
#pragma unroll
  for (int i = 0; i < 4; ++i)
#pragma unroll
    for (int j = 0; j < 4; ++j) {
      const int n = col0 + j * 16;
#pragma unroll
      for (int r = 0; r < 4; ++r) {
        const int m = row0 + i * 16 + r;
        float s = 1.0f / (1.0f + __expf(-acc[i][j][r] * scale));
        C[(size_t)m * S_DIM + n] = (bf16_t)s;
      }
    }
}

extern "C" void kernel_launch(void* const* d_in, const int* in_sizes, int n_in,
                              void* d_out, int out_size, void* d_ws, size_t ws_size,
                              hipStream_t stream) {
  const float* X  = (const float*)d_in[0];
  const float* Wq = (const float*)d_in[1];
  const float* bq = (const float*)d_in[2];
  const float* Wk = (const float*)d_in[3];
  const float* bk = (const float*)d_in[4];
  const float* Wv = (const float*)d_in[5];
  const float* bv = (const float*)d_in[6];
  float* out = (float*)d_out;

  const int M = B_DIM * S_DIM;                 // 16384
  const size_t SD = (size_t)S_DIM * D_DIM;     // 4M per-batch Q/K/V elements
  const size_t E  = (size_t)M * D_DIM;         // 16M
  const size_t PE1 = (size_t)S_DIM * S_DIM;    // 16M (one batch of P)
  const size_t WE = (size_t)D_DIM * D_DIM;

  // PB=2 preferred: P (64 MB) stays L3-resident between scores-write and PV-read.
  auto need = [&](int pb) {
    return (size_t)pb * PE1 * 2 + 2 * E /*Q,K fp8*/ + E * 2 /*Vt bf16*/ + 3 * WE * 2 /*Wt*/;
  };
  const int PB = (ws_size >= need(2)) ? 2 : 1;
  const size_t pbytes = (size_t)PB * PE1 * 2;

  char* wsb = (char*)d_ws;
  bf16_t* P  = (bf16_t*)wsb;   // P region (PB batches)
  bf16_t* Xb = (bf16_t*)wsb;   // aliases P: Xb (32 MB) dead before first P write
  unsigned char* Qb = (unsigned char*)(wsb + pbytes);  // fp8 [16384][1024]
  unsigned char* Kb = Qb + E;                          // fp8
  bf16_t* Vt = (bf16_t*)(Kb + E);                      // bf16 [B][D][S]
  bf16_t* Wt = Vt + E;                                 // bf16 [3072][1024] Wq^T|Wk^T|Wv^T

  // 1. cast X to bf16
  cast_f32_bf16<<<dim3((unsigned)(E / 8 / 256)), dim3(256), 0, stream>>>(X, Xb);

  // 2. transpose+cast weights into concatenated Wt
  dim3 tg(D_DIM / 32, D_DIM / 32), tb(32, 8);
  transpose_cast_1024<<<tg, tb, 0, stream>>>(Wq, Wt);
  transpose_cast_1024<<<tg, tb, 0, stream>>>(Wk, Wt + WE);
  transpose_cast_1024<<<tg, tb, 0, stream>>>(Wv, Wt + 2 * WE);

  // 3. fused QKV projection: [16384,1024] x [3072,1024]^T; Q,K out as fp8, V as bf16^T
  dim3 pg(3 * D_DIM / BN, M / BM, 1);  // (24, 128)
  gemm_bt<0, false><<<pg, 256, 0, stream>>>(Xb, Wt, Qb, Kb, Vt, bq, bk, bv,
                                            D_DIM, D_DIM, D_DIM, D_DIM, 0, 0, 0);

  // 4/5. scores (fp8, sigmoid fused) then PV (bf16), PB batches per iteration
  const float scale = 0.03125f;  // 1/sqrt(1024)
  for (int b0 = 0; b0 < B_DIM; b0 += PB) {
    dim3 sg(S_DIM / BN, S_DIM / BM, PB);  // (32, 32, PB)
    gemm_fp8_sig<<<sg, 256, 0, stream>>>(Qb + (size_t)b0 * SD, Kb + (size_t)b0 * SD, P,
                                         scale, SD, SD, PE1);
    // PV with swapped grid: x = row-blocks so consecutive blocks share a Vt panel
    dim3 vg(S_DIM / BM, D_DIM / BN, PB);  // (32, 8, PB)
    gemm_bt<3, true><<<vg, 256, 0, stream>>>(P, Vt + (size_t)b0 * SD, out + (size_t)b0 * SD,
                                             nullptr, nullptr, nullptr, nullptr, nullptr,
                                             S_DIM, S_DIM, S_DIM, D_DIM,
                                             PE1, SD, SD);
  }
}

// Round 5
// 649.094 us; speedup vs baseline: 1.0660x; 1.0660x over previous
//
#include <hip/hip_runtime.h>
#include <hip/hip_bf16.h>

typedef __bf16 bf16_t;
typedef bf16_t bf16x8 __attribute__((ext_vector_type(8)));
typedef float f32x4 __attribute__((ext_vector_type(4)));

#define GASP const __attribute__((address_space(1))) void*
#define LASP __attribute__((address_space(3))) void*

constexpr int BM = 128, BN = 128, BK = 32;
constexpr int D_DIM = 1024;
constexpr int S_DIM = 4096;
constexpr int B_DIM = 4;

// ---------------- elementwise cast X: fp32 -> bf16 ----------------
__global__ void cast_f32_bf16(const float* __restrict__ in, bf16_t* __restrict__ out) {
  size_t i = ((size_t)blockIdx.x * blockDim.x + threadIdx.x) * 8;
  float4 a = *(const float4*)(in + i);
  float4 b = *(const float4*)(in + i + 4);
  bf16x8 o;
  o[0] = (bf16_t)a.x; o[1] = (bf16_t)a.y; o[2] = (bf16_t)a.z; o[3] = (bf16_t)a.w;
  o[4] = (bf16_t)b.x; o[5] = (bf16_t)b.y; o[6] = (bf16_t)b.z; o[7] = (bf16_t)b.w;
  *(bf16x8*)(out + i) = o;
}

// ---------------- transpose + cast weight: [1024][1024] f32 -> bf16 transposed ----
__global__ void transpose_cast_1024(const float* __restrict__ in, bf16_t* __restrict__ out) {
  __shared__ float t[32][33];
  int x0 = blockIdx.x * 32, y0 = blockIdx.y * 32;
#pragma unroll
  for (int i = 0; i < 32; i += 8)
    t[threadIdx.y + i][threadIdx.x] =
        in[(size_t)(y0 + threadIdx.y + i) * D_DIM + (x0 + threadIdx.x)];
  __syncthreads();
#pragma unroll
  for (int i = 0; i < 32; i += 8)
    out[(size_t)(x0 + threadIdx.y + i) * D_DIM + (y0 + threadIdx.x)] =
        (bf16_t)t[threadIdx.x][threadIdx.y + i];
}

// ---------------- staging: 128x32 bf16 tile -> LDS via global_load_lds (16B/lane) ---------
__device__ __forceinline__ void stage128x32(const bf16_t* __restrict__ g, int ld,
                                            bf16_t* lds, int tid) {
  int r = tid >> 2;
  int c = (tid & 3) * 8;
  const bf16_t* g0 = g + (size_t)r * ld + c;
  const bf16_t* g1 = g0 + (size_t)64 * ld;
  bf16_t* l0 = lds + (tid >> 6) * 512;  // wave-uniform base; HW adds lane*16B
  __builtin_amdgcn_global_load_lds((GASP)g0, (LASP)l0, 16, 0, 0);
  __builtin_amdgcn_global_load_lds((GASP)g1, (LASP)(l0 + 2048), 16, 0, 0);
}

// ---------------- pipelined gemm_bt: C[M,N] = A[M,K] * Bt[N,K]^T, bf16, fp32 acc --------
// Double-buffered K-loop with the prefetch issued AFTER __syncthreads(): at each
// barrier the only outstanding global_load_lds are the CURRENT tile's, which have
// been in flight for a full compute phase — __syncthreads' vmcnt(0) is exactly the
// wait we need, with no drained prefetch (the m97/m99 trap) and no inline asm.
// Buffers are four DISTINCT __shared__ objects (unrolled x2) so alias analysis can
// prove ds_reads don't touch the in-flight DMA destination.
// EPI: 0 = fused QKV (Q,K bf16 row-major + bias; V bf16 transposed Vt[b][d][s] + bias)
//      2 = bf16 out, sigmoid(v*scale)     (scores -> P)
//      3 = fp32 out                        (PV -> out)
// SWAP: x = row-blocks (B-panel L2 locality for PV).
template <int EPI, bool SWAP>
__global__ __launch_bounds__(256) void gemm_bt(
    const bf16_t* __restrict__ A, const bf16_t* __restrict__ Bt,
    void* __restrict__ C0, void* __restrict__ C1, void* __restrict__ C2,
    const float* __restrict__ b0, const float* __restrict__ b1, const float* __restrict__ b2,
    int K, int lda, int ldb, int ldc, float scale,
    size_t sA, size_t sB, size_t sC) {
  __shared__ bf16_t A0[BM * BK], A1[BM * BK];  // 8 KB each
  __shared__ bf16_t B0[BN * BK], B1[BN * BK];  // 32 KB total -> 5 blocks/CU
  const int tid = threadIdx.x;
  const int lane = tid & 63;
  const int w = tid >> 6;
  const int wr = (w >> 1) * 64;
  const int wc = (w & 1) * 64;
  const int fm = lane & 15;
  const int fko = (lane >> 4) * 8;

  const int bx = SWAP ? blockIdx.y : blockIdx.x;
  const int by = SWAP ? blockIdx.x : blockIdx.y;

  const bf16_t* Ag = A + (size_t)blockIdx.z * sA + (size_t)by * BM * lda;
  const bf16_t* Bg = Bt + (size_t)blockIdx.z * sB + (size_t)bx * BN * ldb;

  f32x4 acc[4][4] = {};

  auto compute = [&](const bf16_t* as, const bf16_t* bs) {
    bf16x8 af[4], bfr[4];
#pragma unroll
    for (int i = 0; i < 4; ++i)
      af[i] = *(const bf16x8*)&as[(wr + i * 16 + fm) * BK + fko];
#pragma unroll
    for (int j = 0; j < 4; ++j)
      bfr[j] = *(const bf16x8*)&bs[(wc + j * 16 + fm) * BK + fko];
#pragma unroll
    for (int i = 0; i < 4; ++i)
#pragma unroll
      for (int j = 0; j < 4; ++j)
        acc[i][j] = __builtin_amdgcn_mfma_f32_16x16x32_bf16(af[i], bfr[j], acc[i][j], 0, 0, 0);
  };

  // K/BK is even (32 or 128) for all our shapes.
  stage128x32(Ag, lda, A0, tid);
  stage128x32(Bg, ldb, B0, tid);
  for (int k0 = 0; k0 < K; k0 += 2 * BK) {
    __syncthreads();  // drains ONLY buf0's 4 loads (in flight since last phase)
    {  // prefetch buf1 (always valid: k0+BK <= K-BK)
      stage128x32(Ag + k0 + BK, lda, A1, tid);
      stage128x32(Bg + k0 + BK, ldb, B1, tid);
    }
    compute(A0, B0);
    __syncthreads();  // drains buf1's loads
    if (k0 + 2 * BK < K) {
      stage128x32(Ag + k0 + 2 * BK, lda, A0, tid);
      stage128x32(Bg + k0 + 2 * BK, ldb, B0, tid);
    }
    compute(A1, B1);
  }

  // epilogue: C/D layout col=lane&15, row=(lane>>4)*4+reg
  const int row0 = by * BM + wr + (lane >> 4) * 4;
  const int col0 = bx * BN + wc + fm;

  if constexpr (EPI == 0) {
    const int seg = (bx * BN) >> 10;  // 0=Q, 1=K, 2=V (block cols are 128-aligned)
    const float* bias = (seg == 0) ? b0 : (seg == 1) ? b1 : b2;
#pragma unroll
    for (int i = 0; i < 4; ++i) {
#pragma unroll
      for (int j = 0; j < 4; ++j) {
        const int n = col0 + j * 16;
        const int nl = n & 1023;
        const float bv = bias[nl];
#pragma unroll
        for (int r = 0; r < 4; ++r) {
          const int m = row0 + i * 16 + r;
          float v = acc[i][j][r] + bv;
          if (seg < 2) {
            ((bf16_t*)(seg == 0 ? C0 : C1))[(size_t)m * D_DIM + nl] = (bf16_t)v;
          } else {
            // Vt[b][d][s]: b = m>>12, s = m&4095
            ((bf16_t*)C2)[((size_t)(m >> 12) << 22) + (size_t)nl * S_DIM + (m & (S_DIM - 1))] =
                (bf16_t)v;
          }
        }
      }
    }
  } else {
#pragma unroll
    for (int i = 0; i < 4; ++i) {
#pragma unroll
      for (int j = 0; j < 4; ++j) {
        const int n = col0 + j * 16;
#pragma unroll
        for (int r = 0; r < 4; ++r) {
          const int m = row0 + i * 16 + r;
          float v = acc[i][j][r];
          if constexpr (EPI == 2) {
            float s = 1.0f / (1.0f + __expf(-v * scale));
            ((bf16_t*)C0 + (size_t)blockIdx.z * sC)[(size_t)m * ldc + n] = (bf16_t)s;
          } else {
            ((float*)C0 + (size_t)blockIdx.z * sC)[(size_t)m * ldc + n] = v;
          }
        }
      }
    }
  }
}

extern "C" void kernel_launch(void* const* d_in, const int* in_sizes, int n_in,
                              void* d_out, int out_size, void* d_ws, size_t ws_size,
                              hipStream_t stream) {
  const float* X  = (const float*)d_in[0];
  const float* Wq = (const float*)d_in[1];
  const float* bq = (const float*)d_in[2];
  const float* Wk = (const float*)d_in[3];
  const float* bk = (const float*)d_in[4];
  const float* Wv = (const float*)d_in[5];
  const float* bv = (const float*)d_in[6];
  float* out = (float*)d_out;

  const int M = B_DIM * S_DIM;                 // 16384
  const size_t SD = (size_t)S_DIM * D_DIM;     // 4M per-batch Q/K/V elements
  const size_t E  = (size_t)M * D_DIM;         // 16M
  const size_t PE1 = (size_t)S_DIM * S_DIM;    // 16M (one batch of P)
  const size_t WE = (size_t)D_DIM * D_DIM;

  size_t need4 = (4 * PE1 + 3 * E + 3 * WE) * sizeof(bf16_t);
  const int PB = (ws_size >= need4) ? 4 : 1;
  const size_t psz = (size_t)PB * PE1;

  bf16_t* ws = (bf16_t*)d_ws;
  bf16_t* P   = ws;      // P region
  bf16_t* Xb  = ws;      // aliases P: Xb dead before first P write (same-stream ordering)
  bf16_t* Qb  = ws + psz;
  bf16_t* Kb  = Qb + E;
  bf16_t* Vt  = Kb + E;  // [B][D][S]
  bf16_t* Wt  = Vt + E;  // [3072][1024] concat of Wq^T, Wk^T, Wv^T

  // 1. cast X to bf16
  cast_f32_bf16<<<dim3((unsigned)(E / 8 / 256)), dim3(256), 0, stream>>>(X, Xb);

  // 2. transpose+cast weights into concatenated Wt
  dim3 tg(D_DIM / 32, D_DIM / 32), tb(32, 8);
  transpose_cast_1024<<<tg, tb, 0, stream>>>(Wq, Wt);
  transpose_cast_1024<<<tg, tb, 0, stream>>>(Wk, Wt + WE);
  transpose_cast_1024<<<tg, tb, 0, stream>>>(Wv, Wt + 2 * WE);

  // 3. fused QKV projection: [16384,1024] x [3072,1024]^T
  dim3 pg(3 * D_DIM / BN, M / BM, 1);  // (24, 128)
  gemm_bt<0, false><<<pg, 256, 0, stream>>>(Xb, Wt, Qb, Kb, Vt, bq, bk, bv,
                                            D_DIM, D_DIM, D_DIM, D_DIM, 1.0f, 0, 0, 0);

  // 4/5. scores (sigmoid fused) then PV, PB batches at a time
  const float scale = 0.03125f;  // 1/sqrt(1024)
  for (int b0 = 0; b0 < B_DIM; b0 += PB) {
    dim3 sg(S_DIM / BN, S_DIM / BM, PB);  // (32, 32, PB)
    gemm_bt<2, false><<<sg, 256, 0, stream>>>(Qb + (size_t)b0 * SD, Kb + (size_t)b0 * SD, P,
                                              nullptr, nullptr, nullptr, nullptr, nullptr,
                                              D_DIM, D_DIM, D_DIM, S_DIM, scale,
                                              SD, SD, PE1);
    // PV with swapped grid: x = row-blocks so consecutive blocks share a Vt panel
    dim3 vg(S_DIM / BM, D_DIM / BN, PB);  // (32, 8, PB)
    gemm_bt<3, true><<<vg, 256, 0, stream>>>(P, Vt + (size_t)b0 * SD, out + (size_t)b0 * SD,
                                             nullptr, nullptr, nullptr, nullptr, nullptr,
                                             S_DIM, S_DIM, S_DIM, D_DIM, 1.0f,
                                             PE1, SD, SD);
  }
}

// Round 6
// 645.285 us; speedup vs baseline: 1.0723x; 1.0059x over previous
//
#include <hip/hip_runtime.h>
#include <hip/hip_bf16.h>

typedef __bf16 bf16_t;
typedef bf16_t bf16x8 __attribute__((ext_vector_type(8)));
typedef float f32x16 __attribute__((ext_vector_type(16)));

#define GASP const __attribute__((address_space(1))) void*
#define LASP __attribute__((address_space(3))) void*

constexpr int BM = 128, BN = 128, BK = 32;
constexpr int D_DIM = 1024;
constexpr int S_DIM = 4096;
constexpr int B_DIM = 4;

// ---------------- elementwise cast X: fp32 -> bf16 ----------------
__global__ void cast_f32_bf16(const float* __restrict__ in, bf16_t* __restrict__ out) {
  size_t i = ((size_t)blockIdx.x * blockDim.x + threadIdx.x) * 8;
  float4 a = *(const float4*)(in + i);
  float4 b = *(const float4*)(in + i + 4);
  bf16x8 o;
  o[0] = (bf16_t)a.x; o[1] = (bf16_t)a.y; o[2] = (bf16_t)a.z; o[3] = (bf16_t)a.w;
  o[4] = (bf16_t)b.x; o[5] = (bf16_t)b.y; o[6] = (bf16_t)b.z; o[7] = (bf16_t)b.w;
  *(bf16x8*)(out + i) = o;
}

// ---------------- transpose + cast weight: [1024][1024] f32 -> bf16 transposed ----
__global__ void transpose_cast_1024(const float* __restrict__ in, bf16_t* __restrict__ out) {
  __shared__ float t[32][33];
  int x0 = blockIdx.x * 32, y0 = blockIdx.y * 32;
#pragma unroll
  for (int i = 0; i < 32; i += 8)
    t[threadIdx.y + i][threadIdx.x] =
        in[(size_t)(y0 + threadIdx.y + i) * D_DIM + (x0 + threadIdx.x)];
  __syncthreads();
#pragma unroll
  for (int i = 0; i < 32; i += 8)
    out[(size_t)(x0 + threadIdx.y + i) * D_DIM + (y0 + threadIdx.x)] =
        (bf16_t)t[threadIdx.x][threadIdx.y + i];
}

// ---------------- staging: 128x32 bf16 tile -> LDS via global_load_lds (16B/lane) ---------
__device__ __forceinline__ void stage128x32(const bf16_t* __restrict__ g, int ld,
                                            bf16_t* lds, int tid) {
  int r = tid >> 2;
  int c = (tid & 3) * 8;
  const bf16_t* g0 = g + (size_t)r * ld + c;
  const bf16_t* g1 = g0 + (size_t)64 * ld;
  bf16_t* l0 = lds + (tid >> 6) * 512;  // wave-uniform base; HW adds lane*16B
  __builtin_amdgcn_global_load_lds((GASP)g0, (LASP)l0, 16, 0, 0);
  __builtin_amdgcn_global_load_lds((GASP)g1, (LASP)(l0 + 2048), 16, 0, 0);
}

// ---------------- pipelined gemm_bt: C[M,N] = A[M,K] * Bt[N,K]^T, bf16, fp32 acc --------
// 32x32x16 MFMA: per BK=32 step a wave issues 8 MFMAs (vs 16 with 16x16x32) for the
// same FLOPs — halves the MFMA issue-slot share; scores counters showed the issue
// port (VALU 62% + MFMA 34%) is the binding pipe. Wave tile 64x64 as 2x2 MFMA tiles,
// acc = 4 x f32x16 = 64 VGPRs (same budget as before).
// A-frag: lane reads A[m = tile+lane&31][k = (lane>>5)*8 ..+8]; C/D: col=lane&31,
// row=(reg&3)+8*(reg>>2)+4*(lane>>5)  [HW-verified m74/m101].
// Double-buffered K-loop, prefetch issued after __syncthreads (round-5 structure).
// EPI: 0 = fused QKV (Q,K bf16 row-major + bias; V bf16 transposed Vt[b][d][s] + bias)
//      2 = bf16 out, sigmoid(v*scale)     (scores -> P)
//      3 = fp32 out                        (PV -> out)
// SWAP: x = row-blocks (B-panel L2 locality for PV).
template <int EPI, bool SWAP>
__global__ __launch_bounds__(256) void gemm_bt(
    const bf16_t* __restrict__ A, const bf16_t* __restrict__ Bt,
    void* __restrict__ C0, void* __restrict__ C1, void* __restrict__ C2,
    const float* __restrict__ b0, const float* __restrict__ b1, const float* __restrict__ b2,
    int K, int lda, int ldb, int ldc, float scale,
    size_t sA, size_t sB, size_t sC) {
  __shared__ bf16_t A0[BM * BK], A1[BM * BK];  // 8 KB each
  __shared__ bf16_t B0[BN * BK], B1[BN * BK];  // 32 KB total
  const int tid = threadIdx.x;
  const int lane = tid & 63;
  const int w = tid >> 6;
  const int wr = (w >> 1) * 64;
  const int wc = (w & 1) * 64;
  const int l31 = lane & 31;
  const int lk8 = (lane >> 5) * 8;  // k-octet within the 16-deep MFMA

  const int bx = SWAP ? blockIdx.y : blockIdx.x;
  const int by = SWAP ? blockIdx.x : blockIdx.y;

  const bf16_t* Ag = A + (size_t)blockIdx.z * sA + (size_t)by * BM * lda;
  const bf16_t* Bg = Bt + (size_t)blockIdx.z * sB + (size_t)bx * BN * ldb;

  f32x16 acc[2][2] = {};

  auto compute = [&](const bf16_t* as, const bf16_t* bs) {
#pragma unroll
    for (int h = 0; h < 2; ++h) {  // two K=16 halves of the BK=32 tile
      bf16x8 af[2], bfr[2];
#pragma unroll
      for (int i = 0; i < 2; ++i)
        af[i] = *(const bf16x8*)&as[(wr + i * 32 + l31) * BK + h * 16 + lk8];
#pragma unroll
      for (int j = 0; j < 2; ++j)
        bfr[j] = *(const bf16x8*)&bs[(wc + j * 32 + l31) * BK + h * 16 + lk8];
#pragma unroll
      for (int i = 0; i < 2; ++i)
#pragma unroll
        for (int j = 0; j < 2; ++j)
          acc[i][j] =
              __builtin_amdgcn_mfma_f32_32x32x16_bf16(af[i], bfr[j], acc[i][j], 0, 0, 0);
    }
  };

  // K/BK is even (32 or 128) for all our shapes.
  stage128x32(Ag, lda, A0, tid);
  stage128x32(Bg, ldb, B0, tid);
  for (int k0 = 0; k0 < K; k0 += 2 * BK) {
    __syncthreads();  // drains only buf0's loads (in flight for a full phase)
    stage128x32(Ag + k0 + BK, lda, A1, tid);
    stage128x32(Bg + k0 + BK, ldb, B1, tid);
    compute(A0, B0);
    __syncthreads();
    if (k0 + 2 * BK < K) {
      stage128x32(Ag + k0 + 2 * BK, lda, A0, tid);
      stage128x32(Bg + k0 + 2 * BK, ldb, B0, tid);
    }
    compute(A1, B1);
  }

  // epilogue: C/D layout col=lane&31, row=(reg&3)+8*(reg>>2)+4*(lane>>5)
  const int rbase = by * BM + wr + (lane >> 5) * 4;
  const int cbase = bx * BN + wc + l31;

  if constexpr (EPI == 0) {
    const int seg = (bx * BN) >> 10;  // 0=Q, 1=K, 2=V (block cols are 128-aligned)
    const float* bias = (seg == 0) ? b0 : (seg == 1) ? b1 : b2;
#pragma unroll
    for (int i = 0; i < 2; ++i) {
#pragma unroll
      for (int j = 0; j < 2; ++j) {
        const int n = cbase + j * 32;
        const int nl = n & 1023;
        const float bv = bias[nl];
#pragma unroll
        for (int reg = 0; reg < 16; ++reg) {
          const int m = rbase + i * 32 + (reg & 3) + 8 * (reg >> 2);
          float v = acc[i][j][reg] + bv;
          if (seg < 2) {
            ((bf16_t*)(seg == 0 ? C0 : C1))[(size_t)m * D_DIM + nl] = (bf16_t)v;
          } else {
            // Vt[b][d][s]: b = m>>12, s = m&4095
            ((bf16_t*)C2)[((size_t)(m >> 12) << 22) + (size_t)nl * S_DIM + (m & (S_DIM - 1))] =
                (bf16_t)v;
          }
        }
      }
    }
  } else {
#pragma unroll
    for (int i = 0; i < 2; ++i) {
#pragma unroll
      for (int j = 0; j < 2; ++j) {
        const int n = cbase + j * 32;
#pragma unroll
        for (int reg = 0; reg < 16; ++reg) {
          const int m = rbase + i * 32 + (reg & 3) + 8 * (reg >> 2);
          float v = acc[i][j][reg];
          if constexpr (EPI == 2) {
            float s = 1.0f / (1.0f + __expf(-v * scale));
            ((bf16_t*)C0 + (size_t)blockIdx.z * sC)[(size_t)m * ldc + n] = (bf16_t)s;
          } else {
            ((float*)C0 + (size_t)blockIdx.z * sC)[(size_t)m * ldc + n] = v;
          }
        }
      }
    }
  }
}

extern "C" void kernel_launch(void* const* d_in, const int* in_sizes, int n_in,
                              void* d_out, int out_size, void* d_ws, size_t ws_size,
                              hipStream_t stream) {
  const float* X  = (const float*)d_in[0];
  const float* Wq = (const float*)d_in[1];
  const float* bq = (const float*)d_in[2];
  const float* Wk = (const float*)d_in[3];
  const float* bk = (const float*)d_in[4];
  const float* Wv = (const float*)d_in[5];
  const float* bv = (const float*)d_in[6];
  float* out = (float*)d_out;

  const int M = B_DIM * S_DIM;                 // 16384
  const size_t SD = (size_t)S_DIM * D_DIM;     // 4M per-batch Q/K/V elements
  const size_t E  = (size_t)M * D_DIM;         // 16M
  const size_t PE1 = (size_t)S_DIM * S_DIM;    // 16M (one batch of P)
  const size_t WE = (size_t)D_DIM * D_DIM;

  size_t need4 = (4 * PE1 + 3 * E + 3 * WE) * sizeof(bf16_t);
  const int PB = (ws_size >= need4) ? 4 : 1;
  const size_t psz = (size_t)PB * PE1;

  bf16_t* ws = (bf16_t*)d_ws;
  bf16_t* P   = ws;      // P region
  bf16_t* Xb  = ws;      // aliases P: Xb dead before first P write (same-stream ordering)
  bf16_t* Qb  = ws + psz;
  bf16_t* Kb  = Qb + E;
  bf16_t* Vt  = Kb + E;  // [B][D][S]
  bf16_t* Wt  = Vt + E;  // [3072][1024] concat of Wq^T, Wk^T, Wv^T

  // 1. cast X to bf16
  cast_f32_bf16<<<dim3((unsigned)(E / 8 / 256)), dim3(256), 0, stream>>>(X, Xb);

  // 2. transpose+cast weights into concatenated Wt
  dim3 tg(D_DIM / 32, D_DIM / 32), tb(32, 8);
  transpose_cast_1024<<<tg, tb, 0, stream>>>(Wq, Wt);
  transpose_cast_1024<<<tg, tb, 0, stream>>>(Wk, Wt + WE);
  transpose_cast_1024<<<tg, tb, 0, stream>>>(Wv, Wt + 2 * WE);

  // 3. fused QKV projection: [16384,1024] x [3072,1024]^T
  dim3 pg(3 * D_DIM / BN, M / BM, 1);  // (24, 128)
  gemm_bt<0, false><<<pg, 256, 0, stream>>>(Xb, Wt, Qb, Kb, Vt, bq, bk, bv,
                                            D_DIM, D_DIM, D_DIM, D_DIM, 1.0f, 0, 0, 0);

  // 4/5. scores (sigmoid fused) then PV, PB batches at a time
  const float scale = 0.03125f;  // 1/sqrt(1024)
  for (int b0 = 0; b0 < B_DIM; b0 += PB) {
    dim3 sg(S_DIM / BN, S_DIM / BM, PB);  // (32, 32, PB)
    gemm_bt<2, false><<<sg, 256, 0, stream>>>(Qb + (size_t)b0 * SD, Kb + (size_t)b0 * SD, P,
                                              nullptr, nullptr, nullptr, nullptr, nullptr,
                                              D_DIM, D_DIM, D_DIM, S_DIM, scale,
                                              SD, SD, PE1);
    // PV with swapped grid: x = row-blocks so consecutive blocks share a Vt panel
    dim3 vg(S_DIM / BM, D_DIM / BN, PB);  // (32, 8, PB)
    gemm_bt<3, true><<<vg, 256, 0, stream>>>(P, Vt + (size_t)b0 * SD, out + (size_t)b0 * SD,
                                             nullptr, nullptr, nullptr, nullptr, nullptr,
                                             S_DIM, S_DIM, S_DIM, D_DIM, 1.0f,
                                             PE1, SD, SD);
  }
}